// Round 7
// baseline (405.528 us; speedup 1.0000x reference)
//
#include <hip/hip_runtime.h>

typedef unsigned short u16;
typedef __attribute__((ext_vector_type(8))) short short8;
typedef __attribute__((ext_vector_type(4))) float f32x4;

#define Bn 4096
#define Vn 20
#define Dn 768
#define Mn (Bn * Vn)   // 81920 rows
#define Nn (2 * Dn)    // 1536 packed m1/m2 columns

#define BM 256
#define BNt 256            // Wt rows per block tile (= 128 output e-columns)
#define HK 32              // K per slice
#define NHK (Dn / HK)      // 24 slices
#define NTILES (Nn / BNt)  // 6 N-tiles
#define GRID ((Mn / BM) * NTILES)   // 320 * 6 = 1920, %8 == 0
#define SLOTE 16384        // u16 per slot: A 256x32 (8192) + B 256x32 (8192)

typedef __attribute__((address_space(1))) void GV;
typedef __attribute__((address_space(3))) void LV;

__device__ __forceinline__ u16 f2bf(float f) {
  union { float f; unsigned u; } v; v.f = f;
  unsigned r = v.u + 0x7FFFu + ((v.u >> 16) & 1u);  // round-to-nearest-even
  return (u16)(r >> 16);
}

// LDS layout within a slot matrix region (256 rows x 32 K, u16):
//   u16 index = (r>>1)*64 + (r&1)*32 + (kc ^ ((r>>1)&3))*8 + j
// Row-pair packed into 128B lines + 2-bit chunk XOR: conflict-free
// ds_read_b128 (measured 0 conflicts in R6).
__device__ __forceinline__ int lds_off(int r, int hi) {
  return (r >> 1) * 64 + (r & 1) * 32 + ((hi ^ ((r >> 1) & 3)) * 8);
}

// ---------------- kernel 1: row softmax -> bf16 X ----------------
__global__ __launch_bounds__(192) void softmax_k(const float* __restrict__ vf,
                                                 u16* __restrict__ X) {
  size_t row = blockIdx.x;
  const float4* p = (const float4*)(vf + row * Dn);
  int t = threadIdx.x;
  float4 v = p[t];
  float mx = fmaxf(fmaxf(v.x, v.y), fmaxf(v.z, v.w));
  #pragma unroll
  for (int off = 32; off; off >>= 1) mx = fmaxf(mx, __shfl_xor(mx, off));
  __shared__ float rr[3];
  __shared__ float rs[3];
  int wv = t >> 6, ln = t & 63;
  if (!ln) rr[wv] = mx;
  __syncthreads();
  mx = fmaxf(fmaxf(rr[0], rr[1]), rr[2]);
  float e0 = __expf(v.x - mx), e1 = __expf(v.y - mx);
  float e2 = __expf(v.z - mx), e3 = __expf(v.w - mx);
  float s = e0 + e1 + e2 + e3;
  #pragma unroll
  for (int off = 32; off; off >>= 1) s += __shfl_xor(s, off);
  if (!ln) rs[wv] = s;
  __syncthreads();
  float inv = 1.0f / (rs[0] + rs[1] + rs[2]);
  ushort4 o;
  o.x = f2bf(e0 * inv); o.y = f2bf(e1 * inv);
  o.z = f2bf(e2 * inv); o.w = f2bf(e3 * inv);
  ((ushort4*)(X + row * Dn))[t] = o;
}

// ------- kernel 2: pack W1/W2 block-of-32 interleaved, bf16 [1536][768] -----
__global__ __launch_bounds__(256) void build_wt_k(const float* __restrict__ W1,
                                                  const float* __restrict__ W2,
                                                  u16* __restrict__ Wt) {
  int idx = blockIdx.x * 256 + threadIdx.x;
  if (idx >= Dn * Dn) return;
  int j = idx / Dn, d = idx - j * Dn;
  int b = j >> 5, c = j & 31;
  Wt[(size_t)(b * 64 + c) * Dn + d]      = f2bf(W1[(size_t)j * Dn + d]);
  Wt[(size_t)(b * 64 + 32 + c) * Dn + d] = f2bf(W2[(size_t)j * Dn + d]);
}

// -------- kernel 3: GEMM + fuse, 4-slot ring + register double-buffer -------
// 8 waves (2M x 4N), wave tile 128x64, 24 K-slices of 32.
// Register pipeline (the round-6 fix): cluster1(af,bfr loaded LAST slice)
// runs while af2 reads are in flight; cluster2(af2,bfr) runs while next
// slice's af/bfr reads are in flight. Counted lgkmcnt (DS returns are
// in-order): before c1 outstanding = 8(af,bfr)+4(af2) -> lgkmcnt(4);
// before c2 outstanding = 4(af2)+8(next) -> lgkmcnt(8). LDS pipe (~1152
// cyc/slice/CU) now hides under MFMA (~1242 cyc/slice/CU).
// vmcnt(4) at slice top = slices hk,hk+1 resident (early reads touch slot
// hk+1); stage lead = 2 slices >> HBM latency. Ring safety: stage at slice
// hk writes slot (hk+3)&3, early reads touch (hk+1)&3 — disjoint; all
// slot-hk reads complete (lgkm) before the top-of-hk+1 barrier.
__global__ __launch_bounds__(512, 2) void gemm_fuse_k(
    const u16* __restrict__ X, const u16* __restrict__ Wt,
    const float* __restrict__ b1, const float* __restrict__ b2,
    const float* __restrict__ text, float* __restrict__ out) {
  __shared__ __align__(16) u16 smem[4 * SLOTE];   // 128 KiB

  const int h = blockIdx.x;                      // GRID = 1920 blocks, %8==0
  const int lin = (h & 7) * (GRID / 8) + (h >> 3);
  const int by = lin / NTILES, bx = lin - by * NTILES;
  const int brow = by * BM;

  const int t = threadIdx.x, w = t >> 6, l = t & 63;
  const int lo = l & 15, hi = l >> 4;
  const int wrr = w >> 2, wcc = w & 3;

  // precomputed LDS fragment offsets (u16 units, within slot)
  int offA[4], offA2[4], offB[4];
  #pragma unroll
  for (int m = 0; m < 4; ++m) {
    offA[m]  = lds_off(wrr * 128 + m * 16 + lo, hi);
    offA2[m] = lds_off(wrr * 128 + 64 + m * 16 + lo, hi);
  }
  #pragma unroll
  for (int n = 0; n < 4; ++n)
    offB[n] = 8192 + lds_off(wcc * 64 + n * 16 + lo, hi);

  // staging sources: thread q = i*512+t fills LDS u16 [q*8 .. q*8+8)
  const u16* gA[2];
  const u16* gB[2];
  #pragma unroll
  for (int i = 0; i < 2; ++i) {
    int q = i * 512 + t;
    int rp = q >> 3, half = (q >> 2) & 1, kc = (q & 3) ^ (rp & 3);
    gA[i] = X + (size_t)(brow + rp * 2 + half) * Dn + kc * 8;
    gB[i] = Wt + (size_t)(bx * BNt + rp * 2 + half) * Dn + kc * 8;
  }

#define STAGE_A(s, koff) do { _Pragma("unroll")                                \
    for (int i = 0; i < 2; ++i)                                                \
      __builtin_amdgcn_global_load_lds((GV*)(gA[i] + (koff)),                  \
          (LV*)(smem + (s) * SLOTE + (i * 512 + w * 64) * 8), 16, 0, 0);       \
  } while (0)
#define STAGE_B(s, koff) do { _Pragma("unroll")                                \
    for (int i = 0; i < 2; ++i)                                                \
      __builtin_amdgcn_global_load_lds((GV*)(gB[i] + (koff)),                  \
          (LV*)(smem + (s) * SLOTE + 8192 + (i * 512 + w * 64) * 8), 16, 0, 0);\
  } while (0)

  // prologue: slices 0,1,2 (12 loads)
  STAGE_A(0, 0);       STAGE_B(0, 0);
  STAGE_A(1, HK);      STAGE_B(1, HK);
  STAGE_A(2, 2 * HK);  STAGE_B(2, 2 * HK);
  asm volatile("s_waitcnt vmcnt(8)" ::: "memory");   // slice 0 resident
  __builtin_amdgcn_s_barrier();

  short8 af[4], bfr[4], af2[4];
  #pragma unroll
  for (int m = 0; m < 4; ++m) af[m] = *(const short8*)(smem + offA[m]);
  #pragma unroll
  for (int n = 0; n < 4; ++n) bfr[n] = *(const short8*)(smem + offB[n]);

  f32x4 acc[8][4] = {};

  #pragma unroll
  for (int hk = 0; hk < NHK; ++hk) {
    if (hk <= 21) asm volatile("s_waitcnt vmcnt(4)" ::: "memory");
    else          asm volatile("s_waitcnt vmcnt(0)" ::: "memory");
    __builtin_amdgcn_s_barrier();
    if (hk <= 20) { STAGE_A((hk + 3) & 3, (hk + 3) * HK);
                    STAGE_B((hk + 3) & 3, (hk + 3) * HK); }

    const u16* sc = smem + (hk & 3) * SLOTE;
    const u16* sn = smem + ((hk + 1) & 3) * SLOTE;

    // issue af2 reads (hidden under cluster1)
    #pragma unroll
    for (int m = 0; m < 4; ++m) af2[m] = *(const short8*)(sc + offA2[m]);

    asm volatile("s_waitcnt lgkmcnt(4)" ::: "memory");  // af,bfr ready
    __builtin_amdgcn_sched_barrier(0);
    __builtin_amdgcn_s_setprio(1);
    #pragma unroll
    for (int m = 0; m < 4; ++m)
      #pragma unroll
      for (int n = 0; n < 4; ++n)
        acc[m][n] = __builtin_amdgcn_mfma_f32_16x16x32_bf16(af[m], bfr[n], acc[m][n], 0, 0, 0);
    __builtin_amdgcn_s_setprio(0);

    // issue next-slice af/bfr reads (hidden under cluster2)
    short8 afn[4], bfrn[4];
    if (hk < NHK - 1) {
      #pragma unroll
      for (int m = 0; m < 4; ++m) afn[m] = *(const short8*)(sn + offA[m]);
      #pragma unroll
      for (int n = 0; n < 4; ++n) bfrn[n] = *(const short8*)(sn + offB[n]);
    }

    if (hk < NHK - 1) asm volatile("s_waitcnt lgkmcnt(8)" ::: "memory");  // af2 ready
    else              asm volatile("s_waitcnt lgkmcnt(0)" ::: "memory");
    __builtin_amdgcn_sched_barrier(0);
    __builtin_amdgcn_s_setprio(1);
    #pragma unroll
    for (int m = 0; m < 4; ++m)
      #pragma unroll
      for (int n = 0; n < 4; ++n)
        acc[m + 4][n] = __builtin_amdgcn_mfma_f32_16x16x32_bf16(af2[m], bfr[n], acc[m + 4][n], 0, 0, 0);
    __builtin_amdgcn_s_setprio(0);

    if (hk < NHK - 1) {
      #pragma unroll
      for (int m = 0; m < 4; ++m) af[m] = afn[m];
      #pragma unroll
      for (int n = 0; n < 4; ++n) bfr[n] = bfrn[n];
    }
  }
#undef STAGE_A
#undef STAGE_B

  // epilogue: m1 = acc[m][n], m2 = acc[m][n+2], same lane, same e
  const int ebase = (bx * 4 + wcc) * 32;
  #pragma unroll
  for (int n = 0; n < 2; ++n) {
    const int e = ebase + n * 16 + lo;
    const float B1 = b1[e], B2 = b2[e];
    #pragma unroll
    for (int m = 0; m < 8; ++m) {
      const int gr0 = brow + wrr * 128 + m * 16 + hi * 4;
      #pragma unroll
      for (int r = 0; r < 4; ++r) {
        const int gr = gr0 + r;
        const float v1 = acc[m][n][r] + B1;
        const float v2 = acc[m][n + 2][r] + B2;
        const float tf = text[(size_t)(gr / Vn) * Dn + e];
        out[(size_t)gr * Dn + e] = fmaxf(tf * v1 + v2, 0.0f);
      }
    }
  }
}

// ---------------- kernel 4: conv1 -> relu -> conv2, in-place per row --------
__global__ __launch_bounds__(192) void conv_k(float* __restrict__ out,
                                              const float* __restrict__ cw1,
                                              const float* __restrict__ cb1,
                                              const float* __restrict__ cw2,
                                              const float* __restrict__ cb2) {
  __shared__ float buf[Dn];
  __shared__ float tmp[Dn];
  size_t row = blockIdx.x;
  float* p = out + row * Dn;
  int t = threadIdx.x;
  float4 v = ((const float4*)p)[t];
  ((float4*)buf)[t] = v;
  const float w10 = cw1[0], w11 = cw1[1], w12 = cw1[2], c1b = cb1[0];
  const float w20 = cw2[0], w21 = cw2[1], w22 = cw2[2], c2b = cb2[0];
  __syncthreads();
  float lm = t ? buf[t * 4 - 1] : 0.0f;
  float rp = (t < 191) ? buf[t * 4 + 4] : 0.0f;
  float4 c;
  c.x = fmaxf(w10 * lm  + w11 * v.x + w12 * v.y + c1b, 0.0f);
  c.y = fmaxf(w10 * v.x + w11 * v.y + w12 * v.z + c1b, 0.0f);
  c.z = fmaxf(w10 * v.y + w11 * v.z + w12 * v.w + c1b, 0.0f);
  c.w = fmaxf(w10 * v.z + w11 * v.w + w12 * rp  + c1b, 0.0f);
  ((float4*)tmp)[t] = c;
  __syncthreads();
  float lm2 = t ? tmp[t * 4 - 1] : 0.0f;
  float rp2 = (t < 191) ? tmp[t * 4 + 4] : 0.0f;
  float4 o;
  o.x = w20 * lm2 + w21 * c.x + w22 * c.y + c2b;
  o.y = w20 * c.x + w21 * c.y + w22 * c.z + c2b;
  o.z = w20 * c.y + w21 * c.z + w22 * c.w + c2b;
  o.w = w20 * c.z + w21 * c.w + w22 * rp2 + c2b;
  ((float4*)p)[t] = o;
}

extern "C" void kernel_launch(void* const* d_in, const int* in_sizes, int n_in,
                              void* d_out, int out_size, void* d_ws, size_t ws_size,
                              hipStream_t stream) {
  const float* text = (const float*)d_in[0];
  const float* vf   = (const float*)d_in[1];
  const float* W1   = (const float*)d_in[2];
  const float* b1   = (const float*)d_in[3];
  const float* W2   = (const float*)d_in[4];
  const float* b2   = (const float*)d_in[5];
  const float* cw1  = (const float*)d_in[6];
  const float* cb1  = (const float*)d_in[7];
  const float* cw2  = (const float*)d_in[8];
  const float* cb2  = (const float*)d_in[9];
  float* out = (float*)d_out;

  u16* X  = (u16*)d_ws;                       // [81920][768] bf16 softmax
  u16* Wt = (u16*)d_ws + (size_t)Mn * Dn;     // [1536][768] bf16 packed weights

  softmax_k<<<Mn, 192, 0, stream>>>(vf, X);
  build_wt_k<<<(Dn * Dn + 255) / 256, 256, 0, stream>>>(W1, W2, Wt);
  gemm_fuse_k<<<GRID, 512, 0, stream>>>(X, Wt, b1, b2, text, out);
  conv_k<<<Mn, 192, 0, stream>>>(out, cw1, cb1, cw2, cb2);
}

// Round 8
// 396.207 us; speedup vs baseline: 1.0235x; 1.0235x over previous
//
#include <hip/hip_runtime.h>

typedef unsigned short u16;
typedef __attribute__((ext_vector_type(8))) short short8;
typedef __attribute__((ext_vector_type(4))) float f32x4;

#define Bn 4096
#define Vn 20
#define Dn 768
#define Mn (Bn * Vn)   // 81920 rows
#define Nn (2 * Dn)    // 1536 packed m1/m2 columns

#define BM 256
#define BNt 256            // Wt rows per block tile (= 128 output e-columns)
#define NTILES (Nn / BNt)  // 6 N-tiles
#define GRID ((Mn / BM) * NTILES)   // 320 * 6 = 1920, %8 == 0

typedef __attribute__((address_space(1))) void GV;
typedef __attribute__((address_space(3))) void LV;

__device__ __forceinline__ u16 f2bf(float f) {
  union { float f; unsigned u; } v; v.f = f;
  unsigned r = v.u + 0x7FFFu + ((v.u >> 16) & 1u);  // round-to-nearest-even
  return (u16)(r >> 16);
}

// LDS layout within a 256x32 (rows x K) u16 region:
//   u16 index = (r>>1)*64 + (r&1)*32 + ((kc ^ ((r>>1)&3))*8) + j
// Row-pair packed into 128B lines + 2-bit chunk XOR: measured 0 bank
// conflicts (R6/R7) for both ds_read_b128 and the linear gload_lds writes.
__device__ __forceinline__ int lds_off(int r, int hi) {
  return (r >> 1) * 64 + (r & 1) * 32 + ((hi ^ ((r >> 1) & 3)) * 8);
}

// ---------------- kernel 1: row softmax -> bf16 X ----------------
__global__ __launch_bounds__(192) void softmax_k(const float* __restrict__ vf,
                                                 u16* __restrict__ X) {
  size_t row = blockIdx.x;
  const float4* p = (const float4*)(vf + row * Dn);
  int t = threadIdx.x;
  float4 v = p[t];
  float mx = fmaxf(fmaxf(v.x, v.y), fmaxf(v.z, v.w));
  #pragma unroll
  for (int off = 32; off; off >>= 1) mx = fmaxf(mx, __shfl_xor(mx, off));
  __shared__ float rr[3];
  __shared__ float rs[3];
  int wv = t >> 6, ln = t & 63;
  if (!ln) rr[wv] = mx;
  __syncthreads();
  mx = fmaxf(fmaxf(rr[0], rr[1]), rr[2]);
  float e0 = __expf(v.x - mx), e1 = __expf(v.y - mx);
  float e2 = __expf(v.z - mx), e3 = __expf(v.w - mx);
  float s = e0 + e1 + e2 + e3;
  #pragma unroll
  for (int off = 32; off; off >>= 1) s += __shfl_xor(s, off);
  if (!ln) rs[wv] = s;
  __syncthreads();
  float inv = 1.0f / (rs[0] + rs[1] + rs[2]);
  ushort4 o;
  o.x = f2bf(e0 * inv); o.y = f2bf(e1 * inv);
  o.z = f2bf(e2 * inv); o.w = f2bf(e3 * inv);
  ((ushort4*)(X + row * Dn))[t] = o;
}

// ------- kernel 2: pack W1/W2 block-of-32 interleaved, bf16 [1536][768] -----
__global__ __launch_bounds__(256) void build_wt_k(const float* __restrict__ W1,
                                                  const float* __restrict__ W2,
                                                  u16* __restrict__ Wt) {
  int idx = blockIdx.x * 256 + threadIdx.x;
  if (idx >= Dn * Dn) return;
  int j = idx / Dn, d = idx - j * Dn;
  int b = j >> 5, c = j & 31;
  Wt[(size_t)(b * 64 + c) * Dn + d]      = f2bf(W1[(size_t)j * Dn + d]);
  Wt[(size_t)(b * 64 + 32 + c) * Dn + d] = f2bf(W2[(size_t)j * Dn + d]);
}

// -------- kernel 3: GEMM + fuse, faithful m201 8-phase template -------------
// 8 waves (2M x 4N), wave tile 128x64, BK=64, 2 dbuf slots, K-half half-tiles.
// Phase = {ds_read this phase's frags; stage 1 half-tile; barrier; lgkm0;
//          setprio1; 16 MFMA; setprio0; [vmcnt(4) at P2/P4/P6/P8]; barrier}.
// Per-wave lgkmcnt(0) AFTER the barrier staggers MFMA entry across waves
// (LDS drain overlaps MFMA ramp) — the mechanism R5-R7's counted-prefetch
// variants destroyed by making all waves MFMA-ready simultaneously.
// LDS u16 map: slot s at s*32768; A-Kh k at +k*8192; B-Kh k at +16384+k*8192.
// Load/confirm ledger (verified): prologue L1-16, vmcnt(12) confirms T0-Kh0;
// steady state stages 2 loads/phase, vmcnt(4) at P2/P4/P6/P8 ends keeps 2
// half-tiles in flight and confirms each region >=1 phase before its reads.
__global__ __launch_bounds__(512, 2) void gemm_fuse_k(
    const u16* __restrict__ X, const u16* __restrict__ Wt,
    const float* __restrict__ b1, const float* __restrict__ b2,
    const float* __restrict__ text, float* __restrict__ out) {
  __shared__ __align__(16) u16 smem[65536];   // 128 KiB

  const int h = blockIdx.x;                      // GRID = 1920 blocks, %8==0
  const int lin = (h & 7) * (GRID / 8) + (h >> 3);
  const int by = lin / NTILES, bx = lin - by * NTILES;
  const int brow = by * BM;

  const int t = threadIdx.x, w = t >> 6, l = t & 63;
  const int lo = l & 15, hi = l >> 4;
  const int wrr = w >> 2, wcc = w & 3;

  int offA[8], offB[4];
  #pragma unroll
  for (int m = 0; m < 8; ++m) offA[m] = lds_off(wrr * 128 + m * 16 + lo, hi);
  #pragma unroll
  for (int n = 0; n < 4; ++n) offB[n] = lds_off(wcc * 64 + n * 16 + lo, hi);

  // staging sources: thread q = ii*512+t fills u16 [q*8..q*8+8) of a region
  const u16* gA[2];
  const u16* gB[2];
  #pragma unroll
  for (int ii = 0; ii < 2; ++ii) {
    int q = ii * 512 + t;
    int rp = q >> 3, half = (q >> 2) & 1, kc = (q & 3) ^ (rp & 3);
    gA[ii] = X + (size_t)(brow + rp * 2 + half) * Dn + kc * 8;
    gB[ii] = Wt + (size_t)(bx * BNt + rp * 2 + half) * Dn + kc * 8;
  }

#define STG_A(DST, KOFF) do { _Pragma("unroll")                                \
    for (int ii = 0; ii < 2; ++ii)                                             \
      __builtin_amdgcn_global_load_lds((GV*)(gA[ii] + (KOFF)),                 \
          (LV*)(smem + (DST) + (ii * 512 + w * 64) * 8), 16, 0, 0); } while (0)
#define STG_B(DST, KOFF) do { _Pragma("unroll")                                \
    for (int ii = 0; ii < 2; ++ii)                                             \
      __builtin_amdgcn_global_load_lds((GV*)(gB[ii] + (KOFF)),                 \
          (LV*)(smem + (DST) + (ii * 512 + w * 64) * 8), 16, 0, 0); } while (0)

  // prologue: L1-4 T0Kh0, L5-8 T1Kh0, L9-12 T0Kh1, L13-16 T1Kh1
  STG_A(0, 0);              STG_B(16384, 0);          // T0 Kh0 -> slot0
  STG_A(32768, 64);         STG_B(49152, 64);         // T1 Kh0 -> slot1
  STG_A(8192, 32);          STG_B(24576, 32);         // T0 Kh1
  STG_A(40960, 96);         STG_B(57344, 96);         // T1 Kh1
  asm volatile("s_waitcnt vmcnt(12)" ::: "memory");   // T0-Kh0 resident
  __builtin_amdgcn_s_barrier();

  f32x4 acc[8][4] = {};
  short8 af[8], b0, b1f;

#define PH(SB, KH, NH, NEWA, STG, VM) do {                                     \
    if (NEWA) { _Pragma("unroll") for (int m = 0; m < 8; ++m)                  \
      af[m] = *(const short8*)(smem + (SB) + (KH) * 8192 + offA[m]); }         \
    b0  = *(const short8*)(smem + (SB) + 16384 + (KH) * 8192 + offB[(NH)*2]);  \
    b1f = *(const short8*)(smem + (SB) + 16384 + (KH) * 8192 + offB[(NH)*2+1]);\
    STG;                                                                       \
    __builtin_amdgcn_s_barrier();                                              \
    asm volatile("s_waitcnt lgkmcnt(0)" ::: "memory");                         \
    __builtin_amdgcn_sched_barrier(0);                                         \
    __builtin_amdgcn_s_setprio(1);                                             \
    _Pragma("unroll") for (int m = 0; m < 8; ++m) {                            \
      acc[m][(NH)*2]   = __builtin_amdgcn_mfma_f32_16x16x32_bf16(af[m], b0,  acc[m][(NH)*2],   0, 0, 0); \
      acc[m][(NH)*2+1] = __builtin_amdgcn_mfma_f32_16x16x32_bf16(af[m], b1f, acc[m][(NH)*2+1], 0, 0, 0); \
    }                                                                          \
    __builtin_amdgcn_s_setprio(0);                                             \
    VM;                                                                        \
    __builtin_amdgcn_s_barrier();                                              \
  } while (0)

#define VM4 asm volatile("s_waitcnt vmcnt(4)" ::: "memory")
#define VM0 asm volatile("s_waitcnt vmcnt(0)" ::: "memory")

  #pragma unroll
  for (int i = 0; i < 6; ++i) {
    const int ka = (2 * i + 1) * 64;   // K offset of tile staged into slot1
    const int kb = (2 * i + 2) * 64;   // K offset of tile staged into slot0
    // P1-P4: compute T(2i) from slot0; stage slot1 <- T(2i+1) (i>=1)
    PH(0, 0, 0, true,  if (i >= 1) STG_A(32768, ka),      ;  );                      // P1
    PH(0, 0, 1, false, if (i >= 1) STG_B(49152, ka),      VM4);                      // P2
    PH(0, 1, 0, true,  if (i >= 1) STG_A(40960, ka + 32), ;  );                      // P3
    PH(0, 1, 1, false, if (i >= 1) STG_B(57344, ka + 32), VM4);                      // P4
    // P5-P8: compute T(2i+1) from slot1; stage slot0 <- T(2i+2) (i<=4)
    PH(32768, 0, 0, true,  if (i <= 4) STG_A(0, kb),          ;  );                  // P5
    PH(32768, 0, 1, false, if (i <= 4) STG_B(16384, kb),      if (i == 5) { VM0; } else { VM4; }); // P6
    PH(32768, 1, 0, true,  if (i <= 4) STG_A(8192, kb + 32),  ;  );                  // P7
    PH(32768, 1, 1, false, if (i <= 4) STG_B(24576, kb + 32), if (i <= 4) { VM4; }); // P8
  }
#undef PH
#undef VM4
#undef VM0
#undef STG_A
#undef STG_B

  // epilogue: m1 = acc[m][n], m2 = acc[m][n+2], same lane, same e
  const int ebase = (bx * 4 + wcc) * 32;
  #pragma unroll
  for (int n = 0; n < 2; ++n) {
    const int e = ebase + n * 16 + lo;
    const float Bias1 = b1[e], Bias2 = b2[e];
    #pragma unroll
    for (int m = 0; m < 8; ++m) {
      const int gr0 = brow + wrr * 128 + m * 16 + hi * 4;
      #pragma unroll
      for (int r = 0; r < 4; ++r) {
        const int gr = gr0 + r;
        const float v1 = acc[m][n][r] + Bias1;
        const float v2 = acc[m][n + 2][r] + Bias2;
        const float tf = text[(size_t)(gr / Vn) * Dn + e];
        out[(size_t)gr * Dn + e] = fmaxf(tf * v1 + v2, 0.0f);
      }
    }
  }
}

// ---------------- kernel 4: conv1 -> relu -> conv2, in-place per row --------
__global__ __launch_bounds__(192) void conv_k(float* __restrict__ out,
                                              const float* __restrict__ cw1,
                                              const float* __restrict__ cb1,
                                              const float* __restrict__ cw2,
                                              const float* __restrict__ cb2) {
  __shared__ float buf[Dn];
  __shared__ float tmp[Dn];
  size_t row = blockIdx.x;
  float* p = out + row * Dn;
  int t = threadIdx.x;
  float4 v = ((const float4*)p)[t];
  ((float4*)buf)[t] = v;
  const float w10 = cw1[0], w11 = cw1[1], w12 = cw1[2], c1b = cb1[0];
  const float w20 = cw2[0], w21 = cw2[1], w22 = cw2[2], c2b = cb2[0];
  __syncthreads();
  float lm = t ? buf[t * 4 - 1] : 0.0f;
  float rp = (t < 191) ? buf[t * 4 + 4] : 0.0f;
  float4 c;
  c.x = fmaxf(w10 * lm  + w11 * v.x + w12 * v.y + c1b, 0.0f);
  c.y = fmaxf(w10 * v.x + w11 * v.y + w12 * v.z + c1b, 0.0f);
  c.z = fmaxf(w10 * v.y + w11 * v.z + w12 * v.w + c1b, 0.0f);
  c.w = fmaxf(w10 * v.z + w11 * v.w + w12 * rp  + c1b, 0.0f);
  ((float4*)tmp)[t] = c;
  __syncthreads();
  float lm2 = t ? tmp[t * 4 - 1] : 0.0f;
  float rp2 = (t < 191) ? tmp[t * 4 + 4] : 0.0f;
  float4 o;
  o.x = w20 * lm2 + w21 * c.x + w22 * c.y + c2b;
  o.y = w20 * c.x + w21 * c.y + w22 * c.z + c2b;
  o.z = w20 * c.y + w21 * c.z + w22 * c.w + c2b;
  o.w = w20 * c.z + w21 * c.w + w22 * rp2 + c2b;
  ((float4*)p)[t] = o;
}

extern "C" void kernel_launch(void* const* d_in, const int* in_sizes, int n_in,
                              void* d_out, int out_size, void* d_ws, size_t ws_size,
                              hipStream_t stream) {
  const float* text = (const float*)d_in[0];
  const float* vf   = (const float*)d_in[1];
  const float* W1   = (const float*)d_in[2];
  const float* b1   = (const float*)d_in[3];
  const float* W2   = (const float*)d_in[4];
  const float* b2   = (const float*)d_in[5];
  const float* cw1  = (const float*)d_in[6];
  const float* cb1  = (const float*)d_in[7];
  const float* cw2  = (const float*)d_in[8];
  const float* cb2  = (const float*)d_in[9];
  float* out = (float*)d_out;

  u16* X  = (u16*)d_ws;                       // [81920][768] bf16 softmax
  u16* Wt = (u16*)d_ws + (size_t)Mn * Dn;     // [1536][768] bf16 packed weights

  softmax_k<<<Mn, 192, 0, stream>>>(vf, X);
  build_wt_k<<<(Dn * Dn + 255) / 256, 256, 0, stream>>>(W1, W2, Wt);
  gemm_fuse_k<<<GRID, 512, 0, stream>>>(X, Wt, b1, b2, text, out);
  conv_k<<<Mn, 192, 0, stream>>>(out, cw1, cb1, cw2, cb2);
}

// Round 9
// 374.575 us; speedup vs baseline: 1.0826x; 1.0578x over previous
//
#include <hip/hip_runtime.h>

typedef unsigned short u16;
typedef __attribute__((ext_vector_type(8))) short short8;
typedef __attribute__((ext_vector_type(4))) float f32x4;

#define Bn 4096
#define Vn 20
#define Dn 768
#define Mn (Bn * Vn)   // 81920 rows
#define Nn (2 * Dn)    // 1536 packed m1/m2 columns

#define BM 256
#define BNt 256            // Wt rows per block tile (= 128 output e-columns)
#define NTILES (Nn / BNt)  // 6 N-tiles
#define GRID ((Mn / BM) * NTILES)   // 320 * 6 = 1920, %8 == 0

typedef __attribute__((address_space(1))) void GV;
typedef __attribute__((address_space(3))) void LV;

__device__ __forceinline__ u16 f2bf(float f) {
  union { float f; unsigned u; } v; v.f = f;
  unsigned r = v.u + 0x7FFFu + ((v.u >> 16) & 1u);  // round-to-nearest-even
  return (u16)(r >> 16);
}
__device__ __forceinline__ float bf2f(u16 x) {
  union { unsigned u; float f; } v; v.u = ((unsigned)x) << 16; return v.f;
}

// LDS layout within a 256x32 (rows x K) u16 region (K-loop staging):
//   u16 index = (r>>1)*64 + (r&1)*32 + ((kc ^ ((r>>1)&3))*8) + j
__device__ __forceinline__ int lds_off(int r, int hi) {
  return (r >> 1) * 64 + (r & 1) * 32 + ((hi ^ ((r >> 1) & 3)) * 8);
}

// ---------------- kernel 1: row softmax -> bf16 X ----------------
__global__ __launch_bounds__(192) void softmax_k(const float* __restrict__ vf,
                                                 u16* __restrict__ X) {
  size_t row = blockIdx.x;
  const float4* p = (const float4*)(vf + row * Dn);
  int t = threadIdx.x;
  float4 v = p[t];
  float mx = fmaxf(fmaxf(v.x, v.y), fmaxf(v.z, v.w));
  #pragma unroll
  for (int off = 32; off; off >>= 1) mx = fmaxf(mx, __shfl_xor(mx, off));
  __shared__ float rr[3];
  __shared__ float rs[3];
  int wv = t >> 6, ln = t & 63;
  if (!ln) rr[wv] = mx;
  __syncthreads();
  mx = fmaxf(fmaxf(rr[0], rr[1]), rr[2]);
  float e0 = __expf(v.x - mx), e1 = __expf(v.y - mx);
  float e2 = __expf(v.z - mx), e3 = __expf(v.w - mx);
  float s = e0 + e1 + e2 + e3;
  #pragma unroll
  for (int off = 32; off; off >>= 1) s += __shfl_xor(s, off);
  if (!ln) rs[wv] = s;
  __syncthreads();
  float inv = 1.0f / (rs[0] + rs[1] + rs[2]);
  ushort4 o;
  o.x = f2bf(e0 * inv); o.y = f2bf(e1 * inv);
  o.z = f2bf(e2 * inv); o.w = f2bf(e3 * inv);
  ((ushort4*)(X + row * Dn))[t] = o;
}

// ------- kernel 2: pack W1/W2 block-of-32 interleaved, bf16 [1536][768] -----
__global__ __launch_bounds__(256) void build_wt_k(const float* __restrict__ W1,
                                                  const float* __restrict__ W2,
                                                  u16* __restrict__ Wt) {
  int idx = blockIdx.x * 256 + threadIdx.x;
  if (idx >= Dn * Dn) return;
  int j = idx / Dn, d = idx - j * Dn;
  int b = j >> 5, c = j & 31;
  Wt[(size_t)(b * 64 + c) * Dn + d]      = f2bf(W1[(size_t)j * Dn + d]);
  Wt[(size_t)(b * 64 + 32 + c) * Dn + d] = f2bf(W2[(size_t)j * Dn + d]);
}

// -------- kernel 3: GEMM (R8 8-phase core, unchanged) + FUSED CONV epilogue -
// After the K-loop the 128 KiB LDS is dead: stage fused=relu(text*m1+m2) as
// bf16 col-major [128 cols][256 rows] (XOR swizzle r^=(c&31)<<3 -> optimal
// 8-slot b128 pattern), conv1->relu (E2) and conv2->store (E3) in-block for
// out cols 2..125; seam cols {0..3,124..127} stored to ws for seam_k.
__global__ __launch_bounds__(512, 2) void gemm_fuse_k(
    const u16* __restrict__ X, const u16* __restrict__ Wt,
    const float* __restrict__ b1, const float* __restrict__ b2,
    const float* __restrict__ text, float* __restrict__ out,
    u16* __restrict__ seam,
    const float* __restrict__ cw1, const float* __restrict__ cb1,
    const float* __restrict__ cw2, const float* __restrict__ cb2) {
  __shared__ __align__(16) u16 smem[65536];   // 128 KiB

  const int h = blockIdx.x;                      // GRID = 1920 blocks, %8==0
  const int lin = (h & 7) * (GRID / 8) + (h >> 3);
  const int by = lin / NTILES, bx = lin - by * NTILES;
  const int brow = by * BM;

  const int t = threadIdx.x, w = t >> 6, l = t & 63;
  const int lo = l & 15, hi = l >> 4;
  const int wrr = w >> 2, wcc = w & 3;

  int offA[8], offB[4];
  #pragma unroll
  for (int m = 0; m < 8; ++m) offA[m] = lds_off(wrr * 128 + m * 16 + lo, hi);
  #pragma unroll
  for (int n = 0; n < 4; ++n) offB[n] = lds_off(wcc * 64 + n * 16 + lo, hi);

  const u16* gA[2];
  const u16* gB[2];
  #pragma unroll
  for (int ii = 0; ii < 2; ++ii) {
    int q = ii * 512 + t;
    int rp = q >> 3, half = (q >> 2) & 1, kc = (q & 3) ^ (rp & 3);
    gA[ii] = X + (size_t)(brow + rp * 2 + half) * Dn + kc * 8;
    gB[ii] = Wt + (size_t)(bx * BNt + rp * 2 + half) * Dn + kc * 8;
  }

#define STG_A(DST, KOFF) do { _Pragma("unroll")                                \
    for (int ii = 0; ii < 2; ++ii)                                             \
      __builtin_amdgcn_global_load_lds((GV*)(gA[ii] + (KOFF)),                 \
          (LV*)(smem + (DST) + (ii * 512 + w * 64) * 8), 16, 0, 0); } while (0)
#define STG_B(DST, KOFF) do { _Pragma("unroll")                                \
    for (int ii = 0; ii < 2; ++ii)                                             \
      __builtin_amdgcn_global_load_lds((GV*)(gB[ii] + (KOFF)),                 \
          (LV*)(smem + (DST) + (ii * 512 + w * 64) * 8), 16, 0, 0); } while (0)

  STG_A(0, 0);              STG_B(16384, 0);          // T0 Kh0 -> slot0
  STG_A(32768, 64);         STG_B(49152, 64);         // T1 Kh0 -> slot1
  STG_A(8192, 32);          STG_B(24576, 32);         // T0 Kh1
  STG_A(40960, 96);         STG_B(57344, 96);         // T1 Kh1
  asm volatile("s_waitcnt vmcnt(12)" ::: "memory");   // T0-Kh0 resident
  __builtin_amdgcn_s_barrier();

  f32x4 acc[8][4] = {};
  short8 af[8], bb0, bb1;

#define PH(SB, KH, NH, NEWA, STG, VM) do {                                     \
    if (NEWA) { _Pragma("unroll") for (int m = 0; m < 8; ++m)                  \
      af[m] = *(const short8*)(smem + (SB) + (KH) * 8192 + offA[m]); }         \
    bb0 = *(const short8*)(smem + (SB) + 16384 + (KH) * 8192 + offB[(NH)*2]);  \
    bb1 = *(const short8*)(smem + (SB) + 16384 + (KH) * 8192 + offB[(NH)*2+1]);\
    STG;                                                                       \
    __builtin_amdgcn_s_barrier();                                              \
    asm volatile("s_waitcnt lgkmcnt(0)" ::: "memory");                         \
    __builtin_amdgcn_sched_barrier(0);                                         \
    __builtin_amdgcn_s_setprio(1);                                             \
    _Pragma("unroll") for (int m = 0; m < 8; ++m) {                            \
      acc[m][(NH)*2]   = __builtin_amdgcn_mfma_f32_16x16x32_bf16(af[m], bb0, acc[m][(NH)*2],   0, 0, 0); \
      acc[m][(NH)*2+1] = __builtin_amdgcn_mfma_f32_16x16x32_bf16(af[m], bb1, acc[m][(NH)*2+1], 0, 0, 0); \
    }                                                                          \
    __builtin_amdgcn_s_setprio(0);                                             \
    VM;                                                                        \
    __builtin_amdgcn_s_barrier();                                              \
  } while (0)

#define VM4 asm volatile("s_waitcnt vmcnt(4)" ::: "memory")
#define VM0 asm volatile("s_waitcnt vmcnt(0)" ::: "memory")

  #pragma unroll
  for (int i = 0; i < 6; ++i) {
    const int ka = (2 * i + 1) * 64;
    const int kb = (2 * i + 2) * 64;
    PH(0, 0, 0, true,  if (i >= 1) STG_A(32768, ka),      ;  );
    PH(0, 0, 1, false, if (i >= 1) STG_B(49152, ka),      VM4);
    PH(0, 1, 0, true,  if (i >= 1) STG_A(40960, ka + 32), ;  );
    PH(0, 1, 1, false, if (i >= 1) STG_B(57344, ka + 32), VM4);
    PH(32768, 0, 0, true,  if (i <= 4) STG_A(0, kb),          ;  );
    PH(32768, 0, 1, false, if (i <= 4) STG_B(16384, kb),      if (i == 5) { VM0; } else { VM4; });
    PH(32768, 1, 0, true,  if (i <= 4) STG_A(8192, kb + 32),  ;  );
    PH(32768, 1, 1, false, if (i <= 4) STG_B(24576, kb + 32), if (i <= 4) { VM4; });
  }
#undef PH
#undef VM4
#undef VM0
#undef STG_A
#undef STG_B

  // ======================= fused-conv epilogue ==============================
  // vmcnt==0 here (i=5 P6 drained; P7/P8 stage nothing) -> smem reusable.
  const float w10 = cw1[0], w11 = cw1[1], w12 = cw1[2], c1b = cb1[0];
  const float w20 = cw2[0], w21 = cw2[1], w22 = cw2[2], c2b = cb2[0];

  u16* fsm = smem;           // fused [c][r]: idx = c*256 + (r ^ ((c&31)<<3))
  u16* tsm = smem + 32768;   // tmp, same layout

  // ---- E1: fused -> LDS bf16 (+ seam store for cols 0-3,124-127) ----
  #pragma unroll
  for (int n = 0; n < 2; ++n) {
    const int cl = wcc * 32 + n * 16 + lo;       // local col 0..127
    const int e  = bx * 128 + cl;
    const float B1 = b1[e], B2 = b2[e];
    #pragma unroll
    for (int m = 0; m < 8; ++m) {
      const int rl = wrr * 128 + m * 16 + hi * 4;
      uint2 pk;
      u16* pku = (u16*)&pk;
      #pragma unroll
      for (int r = 0; r < 4; ++r) {
        const int gr = brow + rl + r;
        const float v1 = acc[m][n][r] + B1;
        const float v2 = acc[m][n + 2][r] + B2;
        const float tf = text[(size_t)(gr / Vn) * Dn + e];
        pku[r] = f2bf(fmaxf(tf * v1 + v2, 0.0f));
      }
      *(uint2*)(fsm + cl * 256 + (rl ^ ((cl & 31) << 3))) = pk;
      const int sidx = (cl < 4) ? cl : ((cl >= 124) ? cl - 120 : -1);
      if (sidx >= 0)
        *(uint2*)(seam + ((size_t)(by * 6 + bx) * 8 + sidx) * 256 + rl) = pk;
    }
  }
  __syncthreads();

  // ---- E2: tmp = relu(conv1(fused)), per-thread col; own col kept in regs --
  const int cl = t & 127, rb = t >> 7;
  const int cL = cl ? cl - 1 : 0, cR = (cl < 127) ? cl + 1 : 127;
  short8 tC[8];
  #pragma unroll
  for (int j = 0; j < 8; ++j) {
    const int R = rb * 64 + j * 8;
    short8 sL = *(const short8*)(fsm + cL * 256 + (R ^ ((cL & 31) << 3)));
    short8 sC = *(const short8*)(fsm + cl * 256 + (R ^ ((cl & 31) << 3)));
    short8 sR = *(const short8*)(fsm + cR * 256 + (R ^ ((cR & 31) << 3)));
    short8 o;
    #pragma unroll
    for (int k = 0; k < 8; ++k) {
      float a = bf2f((u16)sL[k]), b = bf2f((u16)sC[k]), c = bf2f((u16)sR[k]);
      float v = fmaxf(fmaf(w10, a, fmaf(w11, b, fmaf(w12, c, c1b))), 0.0f);
      o[k] = (short)f2bf(v);
    }
    *(short8*)(tsm + cl * 256 + (R ^ ((cl & 31) << 3))) = o;
    tC[j] = o;
  }
  __syncthreads();

  // ---- E3: out = conv2(tmp), store interior cols 2..125 ----
  const bool wr_ok = (cl >= 2 && cl <= 125);
  #pragma unroll
  for (int j = 0; j < 8; ++j) {
    const int R = rb * 64 + j * 8;
    short8 tL = *(const short8*)(tsm + cL * 256 + (R ^ ((cL & 31) << 3)));
    short8 tR = *(const short8*)(tsm + cR * 256 + (R ^ ((cR & 31) << 3)));
    #pragma unroll
    for (int k = 0; k < 8; ++k) {
      float v = fmaf(w20, bf2f((u16)tL[k]),
                fmaf(w21, bf2f((u16)tC[j][k]),
                fmaf(w22, bf2f((u16)tR[k]), c2b)));
      if (wr_ok)
        out[(size_t)(brow + R + k) * Dn + bx * 128 + cl] = v;
    }
  }
}

// ------- kernel 4: seam cleanup — out cols {E0,E0+1,E0+126,E0+127} ---------
// Zero-pad semantics: conv2's pad gives tmp(-1)=tmp(768)=0 (NOT conv1 of
// zeros); conv1's pad gives fused(-1)=fused(768)=0 inside tmp(0)/tmp(767).
__global__ __launch_bounds__(256) void seam_k(const u16* __restrict__ seam,
                                              float* __restrict__ out,
                                              const float* __restrict__ cw1,
                                              const float* __restrict__ cb1,
                                              const float* __restrict__ cw2,
                                              const float* __restrict__ cb2) {
  const int bid = blockIdx.x;          // by*6+bx
  const int by = bid / 6, bx = bid - by * 6;
  const int r = threadIdx.x;
  const float w10 = cw1[0], w11 = cw1[1], w12 = cw1[2], c1b = cb1[0];
  const float w20 = cw2[0], w21 = cw2[1], w22 = cw2[2], c2b = cb2[0];
  #define SM(B, I) bf2f(seam[((size_t)(B) * 8 + (I)) * 256 + r])
  float fm2 = 0.f, fm1 = 0.f, fR0 = 0.f, fR1 = 0.f;
  if (bx > 0) { fm2 = SM(bid - 1, 6); fm1 = SM(bid - 1, 7); }
  if (bx < 5) { fR0 = SM(bid + 1, 0); fR1 = SM(bid + 1, 1); }
  const float f0 = SM(bid, 0), f1 = SM(bid, 1), f2 = SM(bid, 2), f3 = SM(bid, 3);
  const float f124 = SM(bid, 4), f125 = SM(bid, 5), f126 = SM(bid, 6), f127 = SM(bid, 7);
  #undef SM
  #define C1(a, b, c) fmaxf(fmaf(w10, (a), fmaf(w11, (b), fmaf(w12, (c), c1b))), 0.0f)
  const float tm1  = (bx > 0) ? C1(fm2, fm1, f0) : 0.0f;   // tmp(-1)=0 at edge
  const float t0   = C1(fm1, f0, f1);
  const float t1   = C1(f0, f1, f2);
  const float t2   = C1(f1, f2, f3);
  const float t125 = C1(f124, f125, f126);
  const float t126 = C1(f125, f126, f127);
  const float t127 = C1(f126, f127, fR0);
  const float t128 = (bx < 5) ? C1(f127, fR0, fR1) : 0.0f;  // tmp(768)=0 at edge
  #undef C1
  const size_t go = (size_t)(by * 256 + r) * Dn + bx * 128;
  out[go + 0]   = fmaf(w20, tm1,  fmaf(w21, t0,   fmaf(w22, t1,   c2b)));
  out[go + 1]   = fmaf(w20, t0,   fmaf(w21, t1,   fmaf(w22, t2,   c2b)));
  out[go + 126] = fmaf(w20, t125, fmaf(w21, t126, fmaf(w22, t127, c2b)));
  out[go + 127] = fmaf(w20, t126, fmaf(w21, t127, fmaf(w22, t128, c2b)));
}

extern "C" void kernel_launch(void* const* d_in, const int* in_sizes, int n_in,
                              void* d_out, int out_size, void* d_ws, size_t ws_size,
                              hipStream_t stream) {
  const float* text = (const float*)d_in[0];
  const float* vf   = (const float*)d_in[1];
  const float* W1   = (const float*)d_in[2];
  const float* b1   = (const float*)d_in[3];
  const float* W2   = (const float*)d_in[4];
  const float* b2   = (const float*)d_in[5];
  const float* cw1  = (const float*)d_in[6];
  const float* cb1  = (const float*)d_in[7];
  const float* cw2  = (const float*)d_in[8];
  const float* cb2  = (const float*)d_in[9];
  float* out = (float*)d_out;

  u16* X    = (u16*)d_ws;                                  // [81920][768] bf16
  u16* Wt   = X + (size_t)Mn * Dn;                         // [1536][768] bf16
  u16* seam = Wt + (size_t)Nn * Dn;                        // [320*6][8][256] bf16

  softmax_k<<<Mn, 192, 0, stream>>>(vf, X);
  build_wt_k<<<(Dn * Dn + 255) / 256, 256, 0, stream>>>(W1, W2, Wt);
  gemm_fuse_k<<<GRID, 512, 0, stream>>>(X, Wt, b1, b2, text, out, seam,
                                        cw1, cb1, cw2, cb2);
  seam_k<<<GRID, 256, 0, stream>>>(seam, out, cw1, cb1, cw2, cb2);
}